// Round 9
// baseline (112.487 us; speedup 1.0000x reference)
//
#include <hip/hip_runtime.h>

#define BATCH 8
#define NPTS 16384
#define MSKEL 1000
#define NCLS 100
#define CKK 10
#define MINDIS_INITF 100000.0f

// ws layout (16B aligned):
//   skelN  : float4[8000]   (-sx,-sy,-sz, 0.5|s|^2) per (b,m)
//   ptsM   : float4[131072] (x,y,z, 0.5|p|^2)       per (b,n)
//   minbits: uint[8000]     per-(b,m) min d^2 as uint bits
#define OFF_PTSM 32000
#define OFF_MINB (32000 + 524288)

// prep: build skelN and ptsM; init minbits to +inf; zero output accumulator.
__global__ __launch_bounds__(256) void k_prep(const float* __restrict__ xyz,
                                              const float* __restrict__ skel,
                                              float4* __restrict__ skelN,
                                              float4* __restrict__ ptsM,
                                              unsigned int* __restrict__ minbits,
                                              float* __restrict__ out) {
    const int gid = blockIdx.x * 256 + threadIdx.x;  // 131072 threads exactly
    {
        const float* p = xyz + (size_t)gid * 6;
        float x = p[0], y = p[1], z = p[2];
        ptsM[gid] = make_float4(x, y, z, 0.5f * (x * x + y * y + z * z));
    }
    if (gid < BATCH * MSKEL) {
        const float* s = skel + (size_t)gid * 3;
        float sx = s[0], sy = s[1], sz = s[2];
        skelN[gid] = make_float4(-sx, -sy, -sz, 0.5f * (sx * sx + sy * sy + sz * sz));
        minbits[gid] = 0x7F800000u;  // +inf
    }
    if (gid == 0) out[0] = 0.0f;
}

// Fused chamfer, 512 blocks x 256 threads (2 blocks/CU, 8 waves/CU).
//   blocks [0,256):   n-side (R7-proven) — 512-pt tile; each LANE owns 8
//                     points, each of 4 WAVES owns a 250-skel uniform slice
//                     → 32 VALU per s_load, ~50 VGPR (no spill). Cross-wave
//                     min via 8 KB LDS, block-sum, atomicAdd (pre-scaled).
//   blocks [256,512): m-side — 512-pt tile; 2 covers of 128 threads (wave-
//                     aligned): each thread owns 8 skel in VGPRs, cover
//                     streams a 256-pt uniform slice → 32 VALU per s_load
//                     (loads halved vs R7) → atomicMin(minbits).
__global__ __launch_bounds__(256) void k_chamfer(const float4* __restrict__ skelN,
                                                 const float4* __restrict__ ptsM,
                                                 unsigned int* __restrict__ minbits,
                                                 float* __restrict__ out) {
    const int bid = blockIdx.x;
    const int tid = threadIdx.x;
    const int wave = tid >> 6, lane = tid & 63;

    if (bid < 256) {
        // ---------------- n-side ----------------
        const int b = bid >> 5, tile = bid & 31;
        const float4* __restrict__ base = ptsM + b * NPTS + tile * 512;

        float4 P[8];
        float mt[8];
#pragma unroll
        for (int j = 0; j < 8; ++j) {
            P[j] = base[j * 64 + lane];  // coalesced dwordx4
            mt[j] = 3.4e38f;
        }

        const float4* __restrict__ sk = skelN + b * MSKEL + wave * 250;
#pragma unroll 5
        for (int m = 0; m < 250; ++m) {
            float4 s = sk[m];  // uniform -> s_load_dwordx4; 32 VALU inst behind it
#pragma unroll
            for (int j = 0; j < 8; ++j) {
                float t = fmaf(P[j].x, s.x, fmaf(P[j].y, s.y, fmaf(P[j].z, s.z, s.w)));
                mt[j] = fminf(mt[j], t);
            }
        }

        // combine across the 4 wave-slices: sm[wave][pt] = mt + 0.5|p|^2
        __shared__ float sm[4 * 512];  // 8 KB
#pragma unroll
        for (int j = 0; j < 8; ++j) {
            sm[wave * 512 + j * 64 + lane] = mt[j] + P[j].w;
        }
        __syncthreads();

        // thread tid finalizes points tid and tid+256
        float a0 = fminf(fminf(sm[tid], sm[512 + tid]),
                         fminf(sm[1024 + tid], sm[1536 + tid]));
        float a1 = fminf(fminf(sm[tid + 256], sm[512 + tid + 256]),
                         fminf(sm[1024 + tid + 256], sm[1536 + tid + 256]));
        float d = sqrtf(fmaxf(2.0f * a0, 1e-12f)) + sqrtf(fmaxf(2.0f * a1, 1e-12f));

#pragma unroll
        for (int o = 32; o > 0; o >>= 1) d += __shfl_down(d, o, 64);
        __shared__ float s_part[4];
        if (lane == 0) s_part[wave] = d;
        __syncthreads();
        if (tid == 0) {
            atomicAdd(out, 0.0125f * (s_part[0] + s_part[1] + s_part[2] + s_part[3]));
        }
    } else {
        // ---------------- m-side ----------------
        const int id = bid - 256;
        const int b = id >> 5, tile = id & 31;
        const int cover = tid >> 7;   // 0 or 1; uniform per wave (flips at wave 2)
        const int local = tid & 127;
        const int m0 = local * 8;     // 8 consecutive skel per thread (1024 >= 1000)

        float4 S[8];
        float mind[8];
#pragma unroll
        for (int k = 0; k < 8; ++k) {
            const int m = m0 + k;
            S[k] = (m < MSKEL) ? skelN[b * MSKEL + m]
                               : make_float4(0.0f, 0.0f, 0.0f, 0.0f);
            mind[k] = 3.4e38f;
        }

        const float4* __restrict__ pp = ptsM + b * NPTS + tile * 512 + cover * 256;
#pragma unroll 4
        for (int n = 0; n < 256; ++n) {
            float4 r = pp[n];  // uniform -> s_load_dwordx4; 32 VALU inst behind it
#pragma unroll
            for (int k = 0; k < 8; ++k) {
                // t = 0.5|p|^2 - p.s ; d^2 = 2(t + 0.5|s|^2)
                float t = fmaf(r.x, S[k].x, fmaf(r.y, S[k].y, fmaf(r.z, S[k].z, r.w)));
                mind[k] = fminf(mind[k], t);
            }
        }
#pragma unroll
        for (int k = 0; k < 8; ++k) {
            const int m = m0 + k;
            if (m < MSKEL) {
                float d2 = 2.0f * (mind[k] + S[k].w);
                // clamp fp-cancellation negatives so uint order == float order
                atomicMin(&minbits[b * MSKEL + m], __float_as_uint(fmaxf(d2, 0.0f)));
            }
        }
    }
}

// reduce: m-side mins (32 KB) + convex-hull term; atomicAdd into out.
__global__ __launch_bounds__(256) void k_reduce(const float* __restrict__ skel,
                                                const int* __restrict__ labels,
                                                const unsigned int* __restrict__ minbits,
                                                float* __restrict__ out) {
    const int gid = blockIdx.x * 256 + threadIdx.x;  // 8 blocks = 2048 threads
    const int tid = threadIdx.x;
    float acc = 0.0f;

    for (int i = gid; i < BATCH * MSKEL; i += 2048) {
        acc += 0.0125f * sqrtf(fmaxf(__uint_as_float(minbits[i]), 1e-12f));
    }

    if (gid < BATCH * NCLS) {
        const int b = gid / NCLS, c = gid - b * NCLS;
        const float* cp = skel + ((size_t)b * MSKEL + c * CKK) * 3;
        const int* lab = labels + (size_t)b * NCLS * CKK + c * CKK;
        float x[CKK], y[CKK], z[CKK];
        int lv[CKK];
#pragma unroll
        for (int i = 0; i < CKK; ++i) {
            x[i] = cp[i * 3 + 0]; y[i] = cp[i * 3 + 1]; z[i] = cp[i * 3 + 2];
            lv[i] = lab[i];
        }
        float convexSum = 0.0f;
#pragma unroll
        for (int i = 0; i < CKK; ++i) {
            if (lv[i] != 1) {
                float mind = MINDIS_INITF;
#pragma unroll
                for (int j = 0; j < CKK; ++j) {
                    if (lv[j] == 1) {
                        float dx = x[i] - x[j], dy = y[i] - y[j], dz = z[i] - z[j];
                        mind = fminf(mind, dx * dx + dy * dy + dz * dz);
                    }
                }
                convexSum += mind;
            }
        }
        acc += convexSum * (1.0f / (BATCH * NCLS));
    }

#pragma unroll
    for (int o = 32; o > 0; o >>= 1) acc += __shfl_down(acc, o, 64);
    __shared__ float s_part[4];
    const int wave = tid >> 6, lane = tid & 63;
    if (lane == 0) s_part[wave] = acc;
    __syncthreads();
    if (tid == 0) {
        atomicAdd(out, s_part[0] + s_part[1] + s_part[2] + s_part[3]);
    }
}

extern "C" void kernel_launch(void* const* d_in, const int* in_sizes, int n_in,
                              void* d_out, int out_size, void* d_ws, size_t ws_size,
                              hipStream_t stream) {
    const float* xyz = (const float*)d_in[0];
    const float* skel = (const float*)d_in[1];
    // d_in[2] = weights (unused by reference)
    const int* labels = (const int*)d_in[3];
    float* out = (float*)d_out;

    float4* skelN = (float4*)d_ws;
    float4* ptsM = (float4*)((float*)d_ws + OFF_PTSM);
    unsigned int* minbits = (unsigned int*)((float*)d_ws + OFF_MINB);

    k_prep<<<512, 256, 0, stream>>>(xyz, skel, skelN, ptsM, minbits, out);
    k_chamfer<<<512, 256, 0, stream>>>(skelN, ptsM, minbits, out);
    k_reduce<<<8, 256, 0, stream>>>(skel, labels, minbits, out);
}

// Round 10
// 106.222 us; speedup vs baseline: 1.0590x; 1.0590x over previous
//
#include <hip/hip_runtime.h>

#define BATCH 8
#define NPTS 16384
#define MSKEL 1000
#define NCLS 100
#define CKK 10
#define MINDIS_INITF 100000.0f

// ws float layout (16B aligned):
//   skelN : float4[8000]    (-sx,-sy,-sz, 0.5|s|^2) per (b,m)
//   ptsM  : float4[131072]  (x,y,z, 0.5|p|^2)       per (b,n)
//   nMins : float[2*131072] per-(half,b,pt) min_t  (t = 0.5|p|^2 - p.s)
//   mTile : float[512*1024] per-(b,tile64,m) min_t + 0.5|s|^2
#define OFF_PTSM 32000
#define OFF_NMIN (32000 + 524288)
#define OFF_MTIL (32000 + 524288 + 262144)

// prep: build skelN and ptsM; zero output accumulator.
__global__ __launch_bounds__(256) void k_prep(const float* __restrict__ xyz,
                                              const float* __restrict__ skel,
                                              float4* __restrict__ skelN,
                                              float4* __restrict__ ptsM,
                                              float* __restrict__ out) {
    const int gid = blockIdx.x * 256 + threadIdx.x;  // 131072 threads exactly
    {
        const float* p = xyz + (size_t)gid * 6;
        float x = p[0], y = p[1], z = p[2];
        ptsM[gid] = make_float4(x, y, z, 0.5f * (x * x + y * y + z * z));
    }
    if (gid < BATCH * MSKEL) {
        const float* s = skel + (size_t)gid * 3;
        float sx = s[0], sy = s[1], sz = s[2];
        skelN[gid] = make_float4(-sx, -sy, -sz, 0.5f * (sx * sx + sy * sy + sz * sz));
    }
    if (gid == 0) out[0] = 0.0f;
}

// Fused chamfer: 1024 blocks x 256 threads (4 blocks/CU, 4 waves/SIMD).
// No atomics; raw partial mins go to ws via coalesced stores.
//   blocks [0,512):    n-side — b=bid>>6; sub=bid&63: tile=sub>>1 (512-pt),
//                      half=sub&1 (500-skel half). Lane owns 8 pts, each of
//                      4 waves owns a 125-skel slice → 32 VALU per s_load.
//                      4-wave LDS min combine → nMins[half][b*16384+pt].
//   blocks [512,1024): m-side — b,tile64 (256-pt tile), 4 skels/thread in
//                      VGPRs → 16 VALU per s_load → mTile[(b*64+t)*1024+m]
//                      coalesced float4 stores.
__global__ __launch_bounds__(256) void k_chamfer(const float4* __restrict__ skelN,
                                                 const float4* __restrict__ ptsM,
                                                 float* __restrict__ nMins,
                                                 float* __restrict__ mTile) {
    const int bid = blockIdx.x;
    const int tid = threadIdx.x;
    const int wave = tid >> 6, lane = tid & 63;

    if (bid < 512) {
        // ---------------- n-side ----------------
        const int b = bid >> 6;
        const int sub = bid & 63;
        const int tile = sub >> 1;
        const int half = sub & 1;
        const float4* __restrict__ base = ptsM + b * NPTS + tile * 512;

        float4 P[8];
        float mt[8];
#pragma unroll
        for (int j = 0; j < 8; ++j) {
            P[j] = base[j * 64 + lane];  // coalesced dwordx4
            mt[j] = 3.4e38f;
        }

        const float4* __restrict__ sk = skelN + b * MSKEL + half * 500 + wave * 125;
#pragma unroll 5
        for (int m = 0; m < 125; ++m) {
            float4 s = sk[m];  // uniform -> s_load_dwordx4; 32 VALU inst behind it
#pragma unroll
            for (int j = 0; j < 8; ++j) {
                float t = fmaf(P[j].x, s.x, fmaf(P[j].y, s.y, fmaf(P[j].z, s.z, s.w)));
                mt[j] = fminf(mt[j], t);
            }
        }

        // combine across the 4 wave-slices: sm[wave][pt] = mt + 0.5|p|^2
        __shared__ float sm[4 * 512];  // 8 KB
#pragma unroll
        for (int j = 0; j < 8; ++j) {
            sm[wave * 512 + j * 64 + lane] = mt[j] + P[j].w;
        }
        __syncthreads();

        float a0 = fminf(fminf(sm[tid], sm[512 + tid]),
                         fminf(sm[1024 + tid], sm[1536 + tid]));
        float a1 = fminf(fminf(sm[tid + 256], sm[512 + tid + 256]),
                         fminf(sm[1024 + tid + 256], sm[1536 + tid + 256]));
        float* dst = nMins + half * (BATCH * NPTS) + b * NPTS + tile * 512;
        dst[tid] = a0;          // coalesced
        dst[tid + 256] = a1;    // coalesced
    } else {
        // ---------------- m-side ----------------
        const int id = bid - 512;
        const int b = id >> 6, tile = id & 63;
        const int m0 = tid * 4;  // 4 consecutive skels (1024 >= 1000)

        float4 S[4];
        float mind[4];
#pragma unroll
        for (int k = 0; k < 4; ++k) {
            const int m = m0 + k;
            const int mi = (m < MSKEL) ? m : (MSKEL - 1);  // clamp (pad lanes)
            S[k] = skelN[b * MSKEL + mi];
            mind[k] = 3.4e38f;
        }

        const float4* __restrict__ pp = ptsM + b * NPTS + tile * 256;
#pragma unroll 8
        for (int n = 0; n < 256; ++n) {
            float4 r = pp[n];  // uniform -> s_load_dwordx4; 16 VALU inst behind it
#pragma unroll
            for (int k = 0; k < 4; ++k) {
                // t = 0.5|p|^2 - p.s
                float t = fmaf(r.x, S[k].x, fmaf(r.y, S[k].y, fmaf(r.z, S[k].z, r.w)));
                mind[k] = fminf(mind[k], t);
            }
        }
        // store v = min_t + 0.5|s|^2  (d^2 = 2 * min over tiles of v)
        float4 v = make_float4(mind[0] + S[0].w, mind[1] + S[1].w,
                               mind[2] + S[2].w, mind[3] + S[3].w);
        float4* dst = (float4*)(mTile + (size_t)(b * 64 + tile) * 1024);
        dst[tid] = v;  // coalesced dwordx4
    }
}

// reduce: n-side half-combine + sqrt-sum (1 MB), m-side 64-way tile min
// (2 MB), convex-hull term; atomicAdd into out.
__global__ __launch_bounds__(256) void k_reduce(const float* __restrict__ skel,
                                                const int* __restrict__ labels,
                                                const float* __restrict__ nMins,
                                                const float* __restrict__ mTile,
                                                float* __restrict__ out) {
    const int gid = blockIdx.x * 256 + threadIdx.x;  // 64 blocks = 16384 threads
    const int tid = threadIdx.x;
    float acc = 0.0f;

    // n-side: 8 points per thread
#pragma unroll
    for (int it = 0; it < 8; ++it) {
        const int i = gid + it * 16384;
        float a = fminf(nMins[i], nMins[BATCH * NPTS + i]);
        acc += 0.0125f * sqrtf(fmaxf(2.0f * a, 1e-12f));  // 0.1 / BATCH
    }

    // m-side: threads 0..8191 → (b,m); 64-way min over tiles
    if (gid < BATCH * 1024) {
        const int b = gid >> 10, m = gid & 1023;
        if (m < MSKEL) {
            const float* src = mTile + (size_t)b * 64 * 1024 + m;
            float mn = 3.4e38f;
#pragma unroll 8
            for (int t = 0; t < 64; ++t) {
                mn = fminf(mn, src[t * 1024]);  // coalesced across lanes
            }
            acc += 0.0125f * sqrtf(fmaxf(2.0f * mn, 1e-12f));
        }
    }

    // convex-hull term: threads 0..799
    if (gid < BATCH * NCLS) {
        const int b = gid / NCLS, c = gid - b * NCLS;
        const float* cp = skel + ((size_t)b * MSKEL + c * CKK) * 3;
        const int* lab = labels + (size_t)b * NCLS * CKK + c * CKK;
        float x[CKK], y[CKK], z[CKK];
        int lv[CKK];
#pragma unroll
        for (int i = 0; i < CKK; ++i) {
            x[i] = cp[i * 3 + 0]; y[i] = cp[i * 3 + 1]; z[i] = cp[i * 3 + 2];
            lv[i] = lab[i];
        }
        float convexSum = 0.0f;
#pragma unroll
        for (int i = 0; i < CKK; ++i) {
            if (lv[i] != 1) {
                float mind = MINDIS_INITF;
#pragma unroll
                for (int j = 0; j < CKK; ++j) {
                    if (lv[j] == 1) {
                        float dx = x[i] - x[j], dy = y[i] - y[j], dz = z[i] - z[j];
                        mind = fminf(mind, dx * dx + dy * dy + dz * dz);
                    }
                }
                convexSum += mind;
            }
        }
        acc += convexSum * (1.0f / (BATCH * NCLS));
    }

#pragma unroll
    for (int o = 32; o > 0; o >>= 1) acc += __shfl_down(acc, o, 64);
    __shared__ float s_part[4];
    const int wave = tid >> 6, lane = tid & 63;
    if (lane == 0) s_part[wave] = acc;
    __syncthreads();
    if (tid == 0) {
        atomicAdd(out, s_part[0] + s_part[1] + s_part[2] + s_part[3]);
    }
}

extern "C" void kernel_launch(void* const* d_in, const int* in_sizes, int n_in,
                              void* d_out, int out_size, void* d_ws, size_t ws_size,
                              hipStream_t stream) {
    const float* xyz = (const float*)d_in[0];
    const float* skel = (const float*)d_in[1];
    // d_in[2] = weights (unused by reference)
    const int* labels = (const int*)d_in[3];
    float* out = (float*)d_out;

    float4* skelN = (float4*)d_ws;
    float4* ptsM = (float4*)((float*)d_ws + OFF_PTSM);
    float* nMins = (float*)d_ws + OFF_NMIN;
    float* mTile = (float*)d_ws + OFF_MTIL;

    k_prep<<<512, 256, 0, stream>>>(xyz, skel, skelN, ptsM, out);
    k_chamfer<<<1024, 256, 0, stream>>>(skelN, ptsM, nMins, mTile);
    k_reduce<<<64, 256, 0, stream>>>(skel, labels, nMins, mTile, out);
}

// Round 11
// 104.076 us; speedup vs baseline: 1.0808x; 1.0206x over previous
//
#include <hip/hip_runtime.h>

#define BATCH 8
#define NPTS 16384
#define MSKEL 1000
#define NCLS 100
#define CKK 10
#define MINDIS_INITF 100000.0f

// ws float layout (16B aligned):
//   skelN : float4[8000]    (-sx,-sy,-sz, 0.5|s|^2) per (b,m)
//   ptsM  : float4[131072]  (x,y,z, 0.5|p|^2)       per (b,n)
//   mTile : float[8*32*1024] per-(b,tile,m) min_t + 0.5|s|^2
#define OFF_PTSM 32000
#define OFF_MTIL (32000 + 524288)

// prep: build skelN and ptsM; zero output accumulator.
__global__ __launch_bounds__(256) void k_prep(const float* __restrict__ xyz,
                                              const float* __restrict__ skel,
                                              float4* __restrict__ skelN,
                                              float4* __restrict__ ptsM,
                                              float* __restrict__ out) {
    const int gid = blockIdx.x * 256 + threadIdx.x;  // 131072 threads exactly
    {
        const float* p = xyz + (size_t)gid * 6;
        float x = p[0], y = p[1], z = p[2];
        ptsM[gid] = make_float4(x, y, z, 0.5f * (x * x + y * y + z * z));
    }
    if (gid < BATCH * MSKEL) {
        const float* s = skel + (size_t)gid * 3;
        float sx = s[0], sy = s[1], sz = s[2];
        skelN[gid] = make_float4(-sx, -sy, -sz, 0.5f * (sx * sx + sy * sy + sz * sz));
    }
    if (gid == 0) out[0] = 0.0f;
}

// Fused chamfer, 512 blocks x 256 threads (2 blocks/CU) — R7 structure.
//   blocks [0,256):   n-side — 512-pt tile; each LANE owns 8 points, each of
//                     4 WAVES owns a 250-skel uniform slice → 32 VALU per
//                     s_load. 4-way LDS min combine, block-sum, one
//                     atomicAdd into out (pre-scaled; 256 atomics total).
//   blocks [256,512): m-side — 4 skel/thread in regs, 512-pt uniform stream
//                     → 16 VALU per s_load; per-tile mins stored PLAIN
//                     (coalesced) to mTile — no atomicMin (R9 showed 524k
//                     device atomics cost ~19 µs; R7's 262k ~5 µs; now 0).
__global__ __launch_bounds__(256) void k_chamfer(const float4* __restrict__ skelN,
                                                 const float4* __restrict__ ptsM,
                                                 float* __restrict__ mTile,
                                                 float* __restrict__ out) {
    const int bid = blockIdx.x;
    const int tid = threadIdx.x;
    const int wave = tid >> 6, lane = tid & 63;

    if (bid < 256) {
        // ---------------- n-side (R7-exact) ----------------
        const int b = bid >> 5, tile = bid & 31;
        const float4* __restrict__ base = ptsM + b * NPTS + tile * 512;

        float4 P[8];
        float mt[8];
#pragma unroll
        for (int j = 0; j < 8; ++j) {
            P[j] = base[j * 64 + lane];  // coalesced dwordx4
            mt[j] = 3.4e38f;
        }

        const float4* __restrict__ sk = skelN + b * MSKEL + wave * 250;
#pragma unroll 5
        for (int m = 0; m < 250; ++m) {
            float4 s = sk[m];  // uniform -> s_load_dwordx4; 32 VALU inst behind it
#pragma unroll
            for (int j = 0; j < 8; ++j) {
                float t = fmaf(P[j].x, s.x, fmaf(P[j].y, s.y, fmaf(P[j].z, s.z, s.w)));
                mt[j] = fminf(mt[j], t);
            }
        }

        // combine across the 4 wave-slices: sm[wave][pt] = mt + 0.5|p|^2
        __shared__ float sm[4 * 512];  // 8 KB
#pragma unroll
        for (int j = 0; j < 8; ++j) {
            sm[wave * 512 + j * 64 + lane] = mt[j] + P[j].w;
        }
        __syncthreads();

        // thread tid finalizes points tid and tid+256
        float a0 = fminf(fminf(sm[tid], sm[512 + tid]),
                         fminf(sm[1024 + tid], sm[1536 + tid]));
        float a1 = fminf(fminf(sm[tid + 256], sm[512 + tid + 256]),
                         fminf(sm[1024 + tid + 256], sm[1536 + tid + 256]));
        float d = sqrtf(fmaxf(2.0f * a0, 1e-12f)) + sqrtf(fmaxf(2.0f * a1, 1e-12f));

#pragma unroll
        for (int o = 32; o > 0; o >>= 1) d += __shfl_down(d, o, 64);
        __shared__ float s_part[4];
        if (lane == 0) s_part[wave] = d;
        __syncthreads();
        if (tid == 0) {
            atomicAdd(out, 0.0125f * (s_part[0] + s_part[1] + s_part[2] + s_part[3]));
        }
    } else {
        // ---------------- m-side (R7 shape, plain stores) ----------------
        const int id = bid - 256;
        const int b = id >> 5, tile = id & 31;

        float4 S[4];
        float mind[4];
#pragma unroll
        for (int k = 0; k < 4; ++k) {
            const int m = tid + k * 256;
            const int mi = (m < MSKEL) ? m : (MSKEL - 1);
            S[k] = skelN[b * MSKEL + mi];  // coalesced
            mind[k] = 3.4e38f;
        }

        const float4* __restrict__ pp = ptsM + b * NPTS + tile * 512;
#pragma unroll 4
        for (int n = 0; n < 512; ++n) {
            float4 r = pp[n];  // uniform -> s_load_dwordx4; 16 VALU inst behind it
#pragma unroll
            for (int k = 0; k < 4; ++k) {
                // t = 0.5|p|^2 - p.s
                float t = fmaf(r.x, S[k].x, fmaf(r.y, S[k].y, fmaf(r.z, S[k].z, r.w)));
                mind[k] = fminf(mind[k], t);
            }
        }
        // store v = min_t + 0.5|s|^2  (d^2 = 2 * min over tiles of v)
        float* tm = mTile + (size_t)(b * 32 + tile) * 1024;
#pragma unroll
        for (int k = 0; k < 4; ++k) {
            const int m = tid + k * 256;
            if (m < MSKEL) tm[m] = mind[k] + S[k].w;  // coalesced per k
        }
    }
}

// reduce: m-side 32-way tile min (1 MB, coalesced) + convex-hull term;
// atomicAdd into out.
__global__ __launch_bounds__(256) void k_reduce(const float* __restrict__ skel,
                                                const int* __restrict__ labels,
                                                const float* __restrict__ mTile,
                                                float* __restrict__ out) {
    const int gid = blockIdx.x * 256 + threadIdx.x;  // 32 blocks = 8192 threads
    const int tid = threadIdx.x;
    float acc = 0.0f;

    {
        const int b = gid >> 10, m = gid & 1023;
        if (m < MSKEL) {
            const float* src = mTile + (size_t)b * 32 * 1024 + m;
            float mn = 3.4e38f;
#pragma unroll 8
            for (int t = 0; t < 32; ++t) {
                mn = fminf(mn, src[t * 1024]);  // coalesced across lanes
            }
            acc += 0.0125f * sqrtf(fmaxf(2.0f * mn, 1e-12f));  // 0.1 / BATCH
        }
    }

    if (gid < BATCH * NCLS) {
        const int b = gid / NCLS, c = gid - b * NCLS;
        const float* cp = skel + ((size_t)b * MSKEL + c * CKK) * 3;
        const int* lab = labels + (size_t)b * NCLS * CKK + c * CKK;
        float x[CKK], y[CKK], z[CKK];
        int lv[CKK];
#pragma unroll
        for (int i = 0; i < CKK; ++i) {
            x[i] = cp[i * 3 + 0]; y[i] = cp[i * 3 + 1]; z[i] = cp[i * 3 + 2];
            lv[i] = lab[i];
        }
        float convexSum = 0.0f;
#pragma unroll
        for (int i = 0; i < CKK; ++i) {
            if (lv[i] != 1) {
                float mind = MINDIS_INITF;
#pragma unroll
                for (int j = 0; j < CKK; ++j) {
                    if (lv[j] == 1) {
                        float dx = x[i] - x[j], dy = y[i] - y[j], dz = z[i] - z[j];
                        mind = fminf(mind, dx * dx + dy * dy + dz * dz);
                    }
                }
                convexSum += mind;
            }
        }
        acc += convexSum * (1.0f / (BATCH * NCLS));
    }

#pragma unroll
    for (int o = 32; o > 0; o >>= 1) acc += __shfl_down(acc, o, 64);
    __shared__ float s_part[4];
    const int wave = tid >> 6, lane = tid & 63;
    if (lane == 0) s_part[wave] = acc;
    __syncthreads();
    if (tid == 0) {
        atomicAdd(out, s_part[0] + s_part[1] + s_part[2] + s_part[3]);
    }
}

extern "C" void kernel_launch(void* const* d_in, const int* in_sizes, int n_in,
                              void* d_out, int out_size, void* d_ws, size_t ws_size,
                              hipStream_t stream) {
    const float* xyz = (const float*)d_in[0];
    const float* skel = (const float*)d_in[1];
    // d_in[2] = weights (unused by reference)
    const int* labels = (const int*)d_in[3];
    float* out = (float*)d_out;

    float4* skelN = (float4*)d_ws;
    float4* ptsM = (float4*)((float*)d_ws + OFF_PTSM);
    float* mTile = (float*)d_ws + OFF_MTIL;

    k_prep<<<512, 256, 0, stream>>>(xyz, skel, skelN, ptsM, out);
    k_chamfer<<<512, 256, 0, stream>>>(skelN, ptsM, mTile, out);
    k_reduce<<<32, 256, 0, stream>>>(skel, labels, mTile, out);
}

// Round 12
// 101.218 us; speedup vs baseline: 1.1113x; 1.0282x over previous
//
#include <hip/hip_runtime.h>

#define BATCH 8
#define NPTS 16384
#define MSKEL 1000
#define NCLS 100
#define CKK 10
#define MINDIS_INITF 100000.0f

// ws float layout (16B aligned):
//   skelN : float4[8000]     (-sx,-sy,-sz, 0.5|s|^2) per (b,m)
//   ptsM  : float4[131072]   (x,y,z, 0.5|p|^2)       per (b,n)
//   mTile : float[8*64*1024] per-(b,tile,m) min_t + 0.5|s|^2
#define OFF_PTSM 32000
#define OFF_MTIL (32000 + 524288)

// prep: build skelN and ptsM; zero output accumulator.
__global__ __launch_bounds__(256) void k_prep(const float* __restrict__ xyz,
                                              const float* __restrict__ skel,
                                              float4* __restrict__ skelN,
                                              float4* __restrict__ ptsM,
                                              float* __restrict__ out) {
    const int gid = blockIdx.x * 256 + threadIdx.x;  // 131072 threads exactly
    {
        const float* p = xyz + (size_t)gid * 6;
        float x = p[0], y = p[1], z = p[2];
        ptsM[gid] = make_float4(x, y, z, 0.5f * (x * x + y * y + z * z));
    }
    if (gid < BATCH * MSKEL) {
        const float* s = skel + (size_t)gid * 3;
        float sx = s[0], sy = s[1], sz = s[2];
        skelN[gid] = make_float4(-sx, -sy, -sz, 0.5f * (sx * sx + sy * sy + sz * sz));
    }
    if (gid == 0) out[0] = 0.0f;
}

// Fused chamfer: 1024 blocks x 256 threads (4 blocks/CU, 4 waves/SIMD).
// Stream operand lives in LDS: wave-uniform ds_read_b128 = HW broadcast
// (conflict-free, ~0 BW) and LDS completes IN-ORDER → compiler can pipeline
// with partial lgkmcnt waits (unlike the SMEM s_load stream of R4-R11, which
// is out-of-order and forces lgkmcnt(0) drains — the measured ~50% VALU cap).
//   blocks [0,512):    n-side — (b, 256-pt tile); all 1000 skels staged in
//                      16 KB LDS; 4 waves split skels 250 each; lane owns 4
//                      pts. Per iter: 1 broadcast ds_read + 16 VALU.
//                      Cross-wave LDS min combine → block atomicAdd (scaled).
//   blocks [512,1024): m-side — (b, 256-pt tile) staged in 4 KB LDS; 4
//                      skel/thread in VGPRs; per iter: 1 broadcast ds_read +
//                      16 VALU. Plain coalesced stores of per-tile mins.
__global__ __launch_bounds__(256) void k_chamfer(const float4* __restrict__ skelN,
                                                 const float4* __restrict__ ptsM,
                                                 float* __restrict__ mTile,
                                                 float* __restrict__ out) {
    __shared__ float4 s_buf[MSKEL];   // n: 1000 skels; m: 256 pts
    __shared__ float s_cmb[4 * 256];  // n: cross-wave combine
    const int bid = blockIdx.x;
    const int tid = threadIdx.x;
    const int wave = tid >> 6, lane = tid & 63;

    if (bid < 512) {
        // ---------------- n-side ----------------
        const int b = bid >> 6, tile = bid & 63;
        for (int i = tid; i < MSKEL; i += 256) {
            s_buf[i] = skelN[b * MSKEL + i];  // coalesced dwordx4 -> ds_write_b128
        }
        const float4* __restrict__ base = ptsM + b * NPTS + tile * 256;
        float4 P[4];
        float mt[4];
#pragma unroll
        for (int j = 0; j < 4; ++j) {
            P[j] = base[j * 64 + lane];  // coalesced dwordx4
            mt[j] = 3.4e38f;
        }
        __syncthreads();

        const float4* __restrict__ sl = s_buf + wave * 250;
#pragma unroll 5
        for (int m = 0; m < 250; ++m) {
            float4 s = sl[m];  // uniform addr -> broadcast ds_read_b128 (in-order)
#pragma unroll
            for (int j = 0; j < 4; ++j) {
                float t = fmaf(P[j].x, s.x, fmaf(P[j].y, s.y, fmaf(P[j].z, s.z, s.w)));
                mt[j] = fminf(mt[j], t);
            }
        }

        // combine across the 4 wave-slices: s_cmb[wave][pt] = mt + 0.5|p|^2
#pragma unroll
        for (int j = 0; j < 4; ++j) {
            s_cmb[wave * 256 + j * 64 + lane] = mt[j] + P[j].w;
        }
        __syncthreads();

        float a = fminf(fminf(s_cmb[tid], s_cmb[256 + tid]),
                        fminf(s_cmb[512 + tid], s_cmb[768 + tid]));
        float d = sqrtf(fmaxf(2.0f * a, 1e-12f));

#pragma unroll
        for (int o = 32; o > 0; o >>= 1) d += __shfl_down(d, o, 64);
        __shared__ float s_part[4];
        if (lane == 0) s_part[wave] = d;
        __syncthreads();
        if (tid == 0) {
            atomicAdd(out, 0.0125f * (s_part[0] + s_part[1] + s_part[2] + s_part[3]));
        }
    } else {
        // ---------------- m-side ----------------
        const int id = bid - 512;
        const int b = id >> 6, tile = id & 63;
        s_buf[tid] = ptsM[b * NPTS + tile * 256 + tid];  // 4 KB stage

        float4 S[4];
        float mind[4];
#pragma unroll
        for (int k = 0; k < 4; ++k) {
            const int m = tid + k * 256;
            const int mi = (m < MSKEL) ? m : (MSKEL - 1);
            S[k] = skelN[b * MSKEL + mi];  // coalesced
            mind[k] = 3.4e38f;
        }
        __syncthreads();

#pragma unroll 8
        for (int n = 0; n < 256; ++n) {
            float4 r = s_buf[n];  // uniform addr -> broadcast ds_read_b128 (in-order)
#pragma unroll
            for (int k = 0; k < 4; ++k) {
                // t = 0.5|p|^2 - p.s
                float t = fmaf(r.x, S[k].x, fmaf(r.y, S[k].y, fmaf(r.z, S[k].z, r.w)));
                mind[k] = fminf(mind[k], t);
            }
        }
        // store v = min_t + 0.5|s|^2  (d^2 = 2 * min over tiles of v)
        float* tm = mTile + (size_t)(b * 64 + tile) * 1024;
#pragma unroll
        for (int k = 0; k < 4; ++k) {
            const int m = tid + k * 256;
            if (m < MSKEL) tm[m] = mind[k] + S[k].w;  // coalesced per k
        }
    }
}

// reduce: m-side 64-way tile min (2 MB, coalesced) + convex-hull term;
// atomicAdd into out.
__global__ __launch_bounds__(256) void k_reduce(const float* __restrict__ skel,
                                                const int* __restrict__ labels,
                                                const float* __restrict__ mTile,
                                                float* __restrict__ out) {
    const int gid = blockIdx.x * 256 + threadIdx.x;  // 32 blocks = 8192 threads
    const int tid = threadIdx.x;
    float acc = 0.0f;

    {
        const int b = gid >> 10, m = gid & 1023;
        if (m < MSKEL) {
            const float* src = mTile + (size_t)b * 64 * 1024 + m;
            float mn = 3.4e38f;
#pragma unroll 8
            for (int t = 0; t < 64; ++t) {
                mn = fminf(mn, src[t * 1024]);  // coalesced across lanes
            }
            acc += 0.0125f * sqrtf(fmaxf(2.0f * mn, 1e-12f));  // 0.1 / BATCH
        }
    }

    if (gid < BATCH * NCLS) {
        const int b = gid / NCLS, c = gid - b * NCLS;
        const float* cp = skel + ((size_t)b * MSKEL + c * CKK) * 3;
        const int* lab = labels + (size_t)b * NCLS * CKK + c * CKK;
        float x[CKK], y[CKK], z[CKK];
        int lv[CKK];
#pragma unroll
        for (int i = 0; i < CKK; ++i) {
            x[i] = cp[i * 3 + 0]; y[i] = cp[i * 3 + 1]; z[i] = cp[i * 3 + 2];
            lv[i] = lab[i];
        }
        float convexSum = 0.0f;
#pragma unroll
        for (int i = 0; i < CKK; ++i) {
            if (lv[i] != 1) {
                float mind = MINDIS_INITF;
#pragma unroll
                for (int j = 0; j < CKK; ++j) {
                    if (lv[j] == 1) {
                        float dx = x[i] - x[j], dy = y[i] - y[j], dz = z[i] - z[j];
                        mind = fminf(mind, dx * dx + dy * dy + dz * dz);
                    }
                }
                convexSum += mind;
            }
        }
        acc += convexSum * (1.0f / (BATCH * NCLS));
    }

#pragma unroll
    for (int o = 32; o > 0; o >>= 1) acc += __shfl_down(acc, o, 64);
    __shared__ float s_part[4];
    const int wave = tid >> 6, lane = tid & 63;
    if (lane == 0) s_part[wave] = acc;
    __syncthreads();
    if (tid == 0) {
        atomicAdd(out, s_part[0] + s_part[1] + s_part[2] + s_part[3]);
    }
}

extern "C" void kernel_launch(void* const* d_in, const int* in_sizes, int n_in,
                              void* d_out, int out_size, void* d_ws, size_t ws_size,
                              hipStream_t stream) {
    const float* xyz = (const float*)d_in[0];
    const float* skel = (const float*)d_in[1];
    // d_in[2] = weights (unused by reference)
    const int* labels = (const int*)d_in[3];
    float* out = (float*)d_out;

    float4* skelN = (float4*)d_ws;
    float4* ptsM = (float4*)((float*)d_ws + OFF_PTSM);
    float* mTile = (float*)d_ws + OFF_MTIL;

    k_prep<<<512, 256, 0, stream>>>(xyz, skel, skelN, ptsM, out);
    k_chamfer<<<1024, 256, 0, stream>>>(skelN, ptsM, mTile, out);
    k_reduce<<<32, 256, 0, stream>>>(skel, labels, mTile, out);
}